// Round 3
// baseline (190.667 us; speedup 1.0000x reference)
//
#include <hip/hip_runtime.h>
#include <stdint.h>

// Correlation via MFMA. out[b,(dy+4)*9+(dx+4),y,x] = (1/128) sum_c F[c,y,x]*S[c,y+dy,x+dx]
//
// R7: barrier-free main kernel + oct-plane prepass.
//  Diagnosis from R6: 136 unified regs (64 VGPR + 72 acc AGPR) -> 3 waves/SIMD
//  (Occupancy 35.8%); per-chunk exposed vmcnt chains on 40 scalar-dword gathers;
//  all pipes <20%. Fixes:
//  - prepass: second -> bf16 oct-planes secp[((b*16+oc)*YP+yp)*XPD+xp] (uint4 =
//    channels 8oc..8oc+7 of one pixel), halos zeroed. Pure register transpose,
//    fully coalesced both sides, no LDS.
//  - main: one global uint4 load IS a B-fragment -> NO LDS staging, NO barriers.
//    2-rows-per-wave m-packing: A lanes = 8px x 2 rows -> acc[10] (40 regs, was 72),
//    56% MFMA efficiency (was 28%), 40 loads : 40 MFMAs per wave.
//    Rolling prefetch: load (kc+1,zi) issued right after cur[zi] consumed ->
//    10-iteration lookahead, counted vmcnt.
//  - epilogue: per-wave LDS transpose -> coalesced float4 stores (keeps WRITE ~40MB).
//  - XCD-chunked bijective swizzle kept (1920 = 8*240).
// LESSON (R2): acc[]/cur[] only ever indexed by fully-unrolled loop vars.
// Fallback: if ws_size < 37.5 MB, run the verified R6 kernel (79.6 us).

typedef __attribute__((ext_vector_type(8))) short bf16x8;
typedef __attribute__((ext_vector_type(4))) float f32x4;

constexpr int Bn = 8, Cn = 128, Hn = 96, Wn = 160;
constexpr int CHS = Hn * Wn;
constexpr int YP  = Hn + 8;     // 104 padded rows (y = yp-4)
constexpr int XPD = Wn + 16;    // 176 padded px   (x = xp-8)
constexpr size_t SECP_OCTS  = (size_t)Bn * 16 * YP * XPD;  // 2,342,912 uint4
constexpr size_t SECP_BYTES = SECP_OCTS * 16;              // 37,486,592 B

__device__ __forceinline__ uint32_t bf16rne(float f) {
    uint32_t u = __float_as_uint(f);
    return (u + 0x7FFFu + ((u >> 16) & 1u)) >> 16;
}
__device__ __forceinline__ uint32_t pk(float a, float b) {
    return bf16rne(a) | (bf16rne(b) << 16);
}

// ---------------- prepass: register transpose to bf16 oct-planes ----------
__global__ __launch_bounds__(256)
void prepass(const float* __restrict__ sec, uint4* __restrict__ secp)
{
    const int idx = blockIdx.x * 256 + threadIdx.x;   // == output uint4 index
    const int xp  = idx % XPD;
    const int t1  = idx / XPD;
    const int yp  = t1 % YP;
    const int t2  = t1 / YP;
    const int oc  = t2 & 15;
    const int b   = t2 >> 4;
    const int y = yp - 4, x = xp - 8;
    uint4 o = make_uint4(0u, 0u, 0u, 0u);
    if (y >= 0 && y < Hn && x >= 0 && x < Wn) {
        // lanes: consecutive idx -> consecutive x  => each of the 8 loads coalesced
        const float* src = sec + ((size_t)b * Cn + 8 * oc) * CHS + (size_t)y * Wn + x;
        float f[8];
        #pragma unroll
        for (int j = 0; j < 8; ++j) f[j] = src[(size_t)j * CHS];
        o.x = pk(f[0], f[1]); o.y = pk(f[2], f[3]);
        o.z = pk(f[4], f[5]); o.w = pk(f[6], f[7]);
    }
    secp[idx] = o;
}

// ---------------- main: barrier-free MFMA kernel ----------------
// Block 256 thr = 4 waves; wave w = (s = w&1 -> 8px strip, rp = w>>1 -> row pair).
// Tile 16px x 4 rows; grid (10, 24, 8) = 1920 blocks.
// Wave output: rows Y = y0+2rp+rh (rh 0/1), px X = x0+8s+(0..7).
// MFMA m = quad*4+reg: rh = m>>3, px = m&7 (A lane n16: rh = n16>>3, px = n16&7).
// B tile for staged row zi (yp = y0+2rp+zi): cols n16 -> xp = x0+8s+4+n16.
//   dxc = n16 - px (0..8 valid), dyc = zi - rh (0..8 valid). 56% of D is useful.
__global__ __launch_bounds__(256, 4)
void corrmain(const float* __restrict__ first, const uint4* __restrict__ secp,
              float* __restrict__ out)
{
    __shared__ float sm[4 * 1952];        // epilogue transpose only (31.2 KB)

    const int tid  = threadIdx.x;
    const int w    = tid >> 6;
    const int lane = tid & 63;
    const int quad = lane >> 4;
    const int n16  = lane & 15;
    const int s    = w & 1;
    const int rp   = w >> 1;

    // bijective XCD-chunked swizzle: 1920 tiles = 8 XCDs x 240; image-major per XCD.
    const int d    = (int)blockIdx.x + 10 * ((int)blockIdx.y + 24 * (int)blockIdx.z);
    const int tile = (d & 7) * 240 + (d >> 3);
    const int b    = tile / 240;
    const int rem  = tile % 240;
    const int y0   = (rem / 10) * 4;
    const int x0   = (rem % 10) * 16;

    // ---- B base: plane oc = 4kc+quad, row yp = y0+2rp+zi, col xp = x0+8s+4+n16 ----
    const uint4* sb = secp
        + ((size_t)(b * 16 + quad) * YP + (y0 + 2 * rp)) * XPD
        + x0 + 8 * s + 4 + n16;

    // prologue: issue kc=0 B-group (10 uint4) first, then gather+pack A (hides B lat.)
    uint4 cur[10];
    #pragma unroll
    for (int zi = 0; zi < 10; ++zi) cur[zi] = sb[(size_t)zi * XPD];

    // ---- A-frags: first[b][32kc+8quad+j][y0+2rp+(n16>>3)][x0+8s+(n16&7)] ----
    bf16x8 aF[4];
    {
        const float* fp = first + (size_t)b * Cn * CHS
                        + (size_t)(y0 + 2 * rp + (n16 >> 3)) * Wn
                        + x0 + 8 * s + (n16 & 7);
        #pragma unroll
        for (int kc = 0; kc < 4; ++kc) {
            float f[8];
            #pragma unroll
            for (int j = 0; j < 8; ++j)
                f[j] = fp[(size_t)(32 * kc + 8 * quad + j) * CHS];
            union { uint32_t u[4]; bf16x8 v; } cv;
            cv.u[0] = pk(f[0], f[1]); cv.u[1] = pk(f[2], f[3]);
            cv.u[2] = pk(f[4], f[5]); cv.u[3] = pk(f[6], f[7]);
            aF[kc] = cv.v;
        }
    }

    f32x4 acc[10];
    #pragma unroll
    for (int zi = 0; zi < 10; ++zi) acc[zi] = (f32x4){0.f, 0.f, 0.f, 0.f};

    // ---- main loop: 40 MFMAs, rolling 10-deep prefetch, zero barriers ----
    #pragma unroll
    for (int kc = 0; kc < 4; ++kc) {
        #pragma unroll
        for (int zi = 0; zi < 10; ++zi) {
            union { uint4 u; bf16x8 v; } bf;
            bf.u = cur[zi];
            if (kc < 3)   // prefetch same zi of next chunk into the freed slot
                cur[zi] = sb[(size_t)((kc + 1) * 4 * YP + zi) * XPD];
            acc[zi] = __builtin_amdgcn_mfma_f32_16x16x32_bf16(
                          aF[kc], bf.v, acc[zi], 0, 0, 0);
        }
    }

    // ---- epilogue: per-wave LDS transpose -> coalesced float4 stores ----
    // buffer [rh][ch=dyc*9+dxc][px], pitch 12 floats (48B, 16B-aligned rows).
    const float inv = 1.0f / 128.0f;
    const int wb = w * 1952;
    #pragma unroll
    for (int zi = 0; zi < 10; ++zi)
        #pragma unroll
        for (int reg = 0; reg < 4; ++reg) {
            const int rh  = quad >> 1;
            const int px  = (quad & 1) * 4 + reg;
            const int dyc = zi - rh;
            const int dxc = n16 - px;
            if (dyc >= 0 && dyc <= 8 && dxc >= 0 && dxc <= 8)
                sm[wb + ((rh * 81) + dyc * 9 + dxc) * 12 + px] = acc[zi][reg] * inv;
        }
    __syncthreads();
    // 2 rh x 81 ch x 2 float4 = 324 slots per wave; 6 rounds over 64 lanes
    float* ob = out + (size_t)b * 81 * CHS + (size_t)(y0 + 2 * rp) * Wn + x0 + 8 * s;
    #pragma unroll
    for (int ii = 0; ii < 6; ++ii) {
        int slot = lane + ii * 64;
        if (slot < 324) {
            int rh  = (slot >= 162) ? 1 : 0;
            int rm  = slot - 162 * rh;
            int c   = rm >> 1, g = rm & 1;
            float4 v = *(const float4*)&sm[wb + (rh * 81 + c) * 12 + 4 * g];
            *(float4*)(ob + (size_t)c * CHS + (size_t)rh * Wn + 4 * g) = v;
        }
    }
}

// ---------------- fallback: verified R6 kernel (79.6 us) ----------------
__global__ __launch_bounds__(512, 4)
void corrfb(const float* __restrict__ first, const float* __restrict__ second,
            float* __restrict__ out)
{
    __shared__ uint4 smem[16 * 32 * 4];

    const int tid  = threadIdx.x;
    const int w    = tid >> 6;
    const int lane = tid & 63;
    const int quad = lane >> 4;
    const int n16  = lane & 15;
    const int r    = w;

    const int d    = (int)blockIdx.x + 10 * ((int)blockIdx.y + 12 * (int)blockIdx.z);
    const int tile = (d & 7) * 120 + (d >> 3);
    const int b    = tile / 120;
    const int rem  = tile % 120;
    const int y0   = (rem / 10) * 8;
    const int x0   = (rem % 10) * 16;
    const int y    = y0 + r;

    const float* sb = second + (size_t)b * Cn * CHS;
    int goff[4], lpos[4];
    bool val[4];
    #pragma unroll
    for (int i = 0; i < 4; ++i) {
        int e   = tid + i * 512;
        int row = e >> 7;
        int xw  = (e >> 2) & 31;
        int q   = e & 3;
        int gy  = y0 + row - 4, gx = x0 + xw - 8;
        val[i]  = (gy >= 0) && (gy < Hn) && (gx >= 0) && (gx < Wn);
        goff[i] = val[i] ? (8 * q * CHS + gy * Wn + gx) : 0;
        lpos[i] = (row * 32 + xw) * 4 + ((q + xw + (xw >> 2)) & 3);
    }

    int bo[2];
    #pragma unroll
    for (int t = 0; t < 2; ++t) {
        int xwr = 16 * t + n16;
        bo[t] = xwr * 4 + ((quad + xwr + (xwr >> 2)) & 3);
    }

    const float* fp = first + (size_t)b * Cn * CHS + (size_t)y * Wn + x0 + n16;

    f32x4 acc[9][2];
    #pragma unroll
    for (int dy = 0; dy < 9; ++dy)
        #pragma unroll
        for (int t = 0; t < 2; ++t)
            acc[dy][t] = (f32x4){0.f, 0.f, 0.f, 0.f};

    float f0[2][8];
    #pragma unroll
    for (int i = 0; i < 2; ++i)
        #pragma unroll
        for (int j = 0; j < 8; ++j)
            f0[i][j] = sb[goff[i] + (size_t)j * CHS];

    #pragma unroll
    for (int kc = 0; kc < 4; ++kc) {
        #pragma unroll
        for (int i = 0; i < 2; ++i) {
            uint4 o;
            o.x = pk(f0[i][0], f0[i][1]); o.y = pk(f0[i][2], f0[i][3]);
            o.z = pk(f0[i][4], f0[i][5]); o.w = pk(f0[i][6], f0[i][7]);
            if (!val[i]) o = make_uint4(0u, 0u, 0u, 0u);
            smem[lpos[i]] = o;
        }
        float f1[2][8], fa[8];
        #pragma unroll
        for (int i = 0; i < 2; ++i)
            #pragma unroll
            for (int j = 0; j < 8; ++j)
                f1[i][j] = sb[goff[2 + i] + (size_t)(32 * kc + j) * CHS];
        #pragma unroll
        for (int j = 0; j < 8; ++j)
            fa[j] = fp[(size_t)(32 * kc + 8 * quad + j) * CHS];
        #pragma unroll
        for (int i = 0; i < 2; ++i) {
            uint4 o;
            o.x = pk(f1[i][0], f1[i][1]); o.y = pk(f1[i][2], f1[i][3]);
            o.z = pk(f1[i][4], f1[i][5]); o.w = pk(f1[i][6], f1[i][7]);
            if (!val[2 + i]) o = make_uint4(0u, 0u, 0u, 0u);
            smem[lpos[2 + i]] = o;
        }
        bf16x8 aF;
        {
            union { uint32_t u[4]; bf16x8 v; } cv;
            cv.u[0] = pk(fa[0], fa[1]); cv.u[1] = pk(fa[2], fa[3]);
            cv.u[2] = pk(fa[4], fa[5]); cv.u[3] = pk(fa[6], fa[7]);
            aF = cv.v;
        }
        __syncthreads();
        if (kc < 3) {
            #pragma unroll
            for (int i = 0; i < 2; ++i)
                #pragma unroll
                for (int j = 0; j < 8; ++j)
                    f0[i][j] = sb[goff[i] + (size_t)(32 * (kc + 1) + j) * CHS];
        }
        #pragma unroll
        for (int dy = 0; dy < 9; ++dy) {
            const int rb = (r + dy) * 128;
            #pragma unroll
            for (int t = 0; t < 2; ++t) {
                union { uint4 u; bf16x8 v; } bf;
                bf.u = smem[rb + bo[t]];
                acc[dy][t] = __builtin_amdgcn_mfma_f32_16x16x32_bf16(
                                 aF, bf.v, acc[dy][t], 0, 0, 0);
            }
        }
        __syncthreads();
    }

    const float inv = 1.0f / 128.0f;
    float* sm = (float*)smem;
    float* ob = out + (size_t)b * 81 * CHS + (size_t)y * Wn + x0;
    const int wb = w * 540;
    #pragma unroll
    for (int ck = 0; ck < 3; ++ck) {
        #pragma unroll
        for (int dd = 0; dd < 3; ++dd)
            #pragma unroll
            for (int t = 0; t < 2; ++t)
                #pragma unroll
                for (int reg = 0; reg < 4; ++reg) {
                    int mm  = quad * 4 + reg;
                    int dxc = 16 * t + n16 - mm - 4;
                    if (dxc >= 0 && dxc <= 8)
                        sm[wb + (dd * 9 + dxc) * 20 + mm] = acc[ck * 3 + dd][t][reg] * inv;
                }
        __syncthreads();
        #pragma unroll
        for (int ii = 0; ii < 2; ++ii) {
            int slot = lane + ii * 64;
            if (slot < 108) {
                int chn = slot >> 2, g = slot & 3;
                float4 v = *(const float4*)&sm[wb + chn * 20 + 4 * g];
                int ch = (ck * 3 + chn / 9) * 9 + chn % 9;
                *(float4*)(ob + (size_t)ch * CHS + 4 * g) = v;
            }
        }
        __syncthreads();
    }
}

extern "C" void kernel_launch(void* const* d_in, const int* in_sizes, int n_in,
                              void* d_out, int out_size, void* d_ws, size_t ws_size,
                              hipStream_t stream) {
    (void)in_sizes; (void)n_in; (void)out_size;
    const float* first  = (const float*)d_in[0];
    const float* second = (const float*)d_in[1];
    float* out = (float*)d_out;

    if (ws_size >= SECP_BYTES) {
        uint4* secp = (uint4*)d_ws;
        prepass<<<dim3((unsigned)(SECP_OCTS / 256), 1, 1), dim3(256, 1, 1), 0, stream>>>(
            second, secp);
        corrmain<<<dim3(10, 24, 8), dim3(256, 1, 1), 0, stream>>>(first, secp, out);
    } else {
        corrfb<<<dim3(Wn / 16, Hn / 8, Bn), dim3(512, 1, 1), 0, stream>>>(
            first, second, out);
    }
}

// Round 4
// 177.690 us; speedup vs baseline: 1.0730x; 1.0730x over previous
//
#include <hip/hip_runtime.h>
#include <stdint.h>

// Correlation via MFMA. out[b,(dy+4)*9+(dx+4),y,x] = (1/128) sum_c F[c,y,x]*S[c,y+dy,x+dx]
//
// R8: kill the load serialization.
//  Diagnosis from R7 counters: wave residency = Occ% x 32 x 256 x dur / waves ~= 60K
//  cycles/wave for ~70 loads + 40 MFMAs -> loads were fully SERIALIZED. Cause:
//  register demand (cur[10]+aF+acc ~130) > launch_bounds cap (128) -> allocator
//  recycled a few VGPRs for all loads, destroying memory-level parallelism.
//  Fixes:
//  - B staging via __builtin_amdgcn_global_load_lds (16B/lane, ZERO VGPR cost),
//    from the padded secp oct-planes (padding => no per-lane predication, the
//    prerequisite for lds-direct). Double-buffered LDS, 1 barrier/chunk,
//    stage(kc+1) issued BEFORE compute(kc) (m97 pattern).
//  - A-gather as 32 named-register parallel loads (fA[4][8], transient) -> full MLP.
//  - Steady register demand ~75 << 128 cap -> compiler has slack, keeps pipelining.
//  - Tile 16px x 8 rows (8 waves, 512 thr), grid 960, bijective XCD swizzle kept.
//  - B-frag = one ds_read_b128 (bank-uniform: 8 lanes per 4-bank group = optimal).
//  - Epilogue: R7's verified per-wave LDS transpose -> float4 stores (WRITE ~40MB).
// LESSON (R2): acc[]/fA[] only ever indexed by fully-unrolled loop vars.
// Fallback: if ws_size < 37.5 MB, run the verified R6 kernel (79.6 us).

typedef __attribute__((ext_vector_type(8))) short bf16x8;
typedef __attribute__((ext_vector_type(4))) float f32x4;

constexpr int Bn = 8, Cn = 128, Hn = 96, Wn = 160;
constexpr int CHS = Hn * Wn;
constexpr int YP  = Hn + 8;     // 104 padded rows (y = yp-4)
constexpr int XPD = Wn + 16;    // 176 padded px   (x = xp-8)
constexpr size_t SECP_OCTS  = (size_t)Bn * 16 * YP * XPD;  // 2,342,912 uint4
constexpr size_t SECP_BYTES = SECP_OCTS * 16;              // 37,486,592 B

__device__ __forceinline__ uint32_t bf16rne(float f) {
    uint32_t u = __float_as_uint(f);
    return (u + 0x7FFFu + ((u >> 16) & 1u)) >> 16;
}
__device__ __forceinline__ uint32_t pk(float a, float b) {
    return bf16rne(a) | (bf16rne(b) << 16);
}

// ---------------- prepass: register transpose to bf16 oct-planes (R7, verified) ----
__global__ __launch_bounds__(256)
void prepass(const float* __restrict__ sec, uint4* __restrict__ secp)
{
    const int idx = blockIdx.x * 256 + threadIdx.x;   // == output uint4 index
    const int xp  = idx % XPD;
    const int t1  = idx / XPD;
    const int yp  = t1 % YP;
    const int t2  = t1 / YP;
    const int oc  = t2 & 15;
    const int b   = t2 >> 4;
    const int y = yp - 4, x = xp - 8;
    uint4 o = make_uint4(0u, 0u, 0u, 0u);
    if (y >= 0 && y < Hn && x >= 0 && x < Wn) {
        const float* src = sec + ((size_t)b * Cn + 8 * oc) * CHS + (size_t)y * Wn + x;
        float f[8];
        #pragma unroll
        for (int j = 0; j < 8; ++j) f[j] = src[(size_t)j * CHS];
        o.x = pk(f[0], f[1]); o.y = pk(f[2], f[3]);
        o.z = pk(f[4], f[5]); o.w = pk(f[6], f[7]);
    }
    secp[idx] = o;
}

// ---------------- main: LDS-direct double-buffered MFMA kernel ----------------
// Block 512 thr = 8 waves; wave w = (s = w&1 -> 8px strip, rp = w>>1 -> row pair 0..3).
// Tile 16px x 8 rows; grid (10, 12, 8) = 960 blocks, bijective XCD swizzle.
// Staged per chunk: 4 oc-planes x 16 rows x 24 px octs = 1536 uint4 = 24.6 KB,
//   slot sig = q*384 + row*24 + xw  (xp = x0+4+xw, yp = y0+row). Double buffered.
// Wave output rows Y = y0+2rp+rh (rh = n16>>3), px X = x0+8s+(n16&7).
// B tile for zi: LDS slot quad*384 + (2rp+zi)*24 + 8s+n16 -> one ds_read_b128.
//   dxc = n16 - px (0..8), dyc = zi - rh (0..8).
__global__ __launch_bounds__(512, 4)
void corrmain(const float* __restrict__ first, const uint4* __restrict__ secp,
              float* __restrict__ out)
{
    __shared__ __align__(16) char smemRaw[62464];   // max(2*24576 stage, 62464 epi)
    uint4* smemS = (uint4*)smemRaw;
    float* smE   = (float*)smemRaw;

    const int tid  = threadIdx.x;
    const int w    = tid >> 6;
    const int lane = tid & 63;
    const int quad = lane >> 4;
    const int n16  = lane & 15;
    const int s    = w & 1;
    const int rp   = w >> 1;

    // bijective XCD-chunked swizzle: 960 tiles = 8 XCDs x 120; image-major per XCD.
    const int d    = (int)blockIdx.x + 10 * ((int)blockIdx.y + 12 * (int)blockIdx.z);
    const int tile = (d & 7) * 120 + (d >> 3);
    const int b    = tile / 120;
    const int rem  = tile % 120;
    const int y0   = (rem / 10) * 8;
    const int x0   = (rem % 10) * 16;

    // ---- staging descriptors: 3 slots/thread; source per-lane, LDS dest wave-linear
    size_t gsl[3];
    #pragma unroll
    for (int i = 0; i < 3; ++i) {
        int sig = i * 512 + tid;
        int q   = sig / 384;
        int rm  = sig % 384;
        int row = rm / 24;
        int xw  = rm % 24;
        gsl[i] = ((size_t)(b * 16 + q) * YP + (y0 + row)) * XPD + (x0 + 4 + xw);
    }
    const size_t kstep = (size_t)4 * YP * XPD;   // oc += 4 per chunk

    // stage chunk 0 into buffer 0 (zero-VGPR async loads)
    #pragma unroll
    for (int i = 0; i < 3; ++i)
        __builtin_amdgcn_global_load_lds(
            (const uint32_t*)(secp + gsl[i]),
            (uint32_t*)(smemS + i * 512 + w * 64),
            16, 0, 0);

    // ---- A-frags: 32 independent named-register loads, then pack ----
    bf16x8 aF[4];
    {
        const float* fp = first + (size_t)b * Cn * CHS
                        + (size_t)(y0 + 2 * rp + (n16 >> 3)) * Wn
                        + x0 + 8 * s + (n16 & 7);
        float fA[4][8];
        #pragma unroll
        for (int kc = 0; kc < 4; ++kc)
            #pragma unroll
            for (int j = 0; j < 8; ++j)
                fA[kc][j] = fp[(size_t)(32 * kc + 8 * quad + j) * CHS];
        #pragma unroll
        for (int kc = 0; kc < 4; ++kc) {
            union { uint32_t u[4]; bf16x8 v; } cv;
            cv.u[0] = pk(fA[kc][0], fA[kc][1]); cv.u[1] = pk(fA[kc][2], fA[kc][3]);
            cv.u[2] = pk(fA[kc][4], fA[kc][5]); cv.u[3] = pk(fA[kc][6], fA[kc][7]);
            aF[kc] = cv.v;
        }
    }

    f32x4 acc[10];
    #pragma unroll
    for (int zi = 0; zi < 10; ++zi) acc[zi] = (f32x4){0.f, 0.f, 0.f, 0.f};

    __syncthreads();   // chunk 0 staged (compiler drains vmcnt before s_barrier)

    // ---- main loop: stage(kc+1) issued early, compute kc, one barrier/chunk ----
    #pragma unroll
    for (int kc = 0; kc < 4; ++kc) {
        if (kc < 3) {
            const int nb = (kc + 1) & 1;
            #pragma unroll
            for (int i = 0; i < 3; ++i)
                __builtin_amdgcn_global_load_lds(
                    (const uint32_t*)(secp + gsl[i] + kstep * (kc + 1)),
                    (uint32_t*)(smemS + nb * 1536 + i * 512 + w * 64),
                    16, 0, 0);
        }
        const int cb = (kc & 1) * 1536;
        #pragma unroll
        for (int zi = 0; zi < 10; ++zi) {
            union { uint4 u; bf16x8 v; } bf;
            bf.u = smemS[cb + quad * 384 + (2 * rp + zi) * 24 + 8 * s + n16];
            acc[zi] = __builtin_amdgcn_mfma_f32_16x16x32_bf16(
                          aF[kc], bf.v, acc[zi], 0, 0, 0);
        }
        __syncthreads();   // stage(kc+1) done + buffer kc&1 free for kc+2
    }

    // ---- epilogue (R7 verified): per-wave LDS transpose -> coalesced float4 ----
    const float inv = 1.0f / 128.0f;
    const int wb = w * 1952;
    #pragma unroll
    for (int zi = 0; zi < 10; ++zi)
        #pragma unroll
        for (int reg = 0; reg < 4; ++reg) {
            const int rh  = quad >> 1;
            const int px  = (quad & 1) * 4 + reg;
            const int dyc = zi - rh;
            const int dxc = n16 - px;
            if (dyc >= 0 && dyc <= 8 && dxc >= 0 && dxc <= 8)
                smE[wb + ((rh * 81) + dyc * 9 + dxc) * 12 + px] = acc[zi][reg] * inv;
        }
    __syncthreads();
    float* ob = out + (size_t)b * 81 * CHS + (size_t)(y0 + 2 * rp) * Wn + x0 + 8 * s;
    #pragma unroll
    for (int ii = 0; ii < 6; ++ii) {
        int slot = lane + ii * 64;
        if (slot < 324) {
            int rh  = (slot >= 162) ? 1 : 0;
            int rm2 = slot - 162 * rh;
            int c   = rm2 >> 1, g = rm2 & 1;
            float4 v = *(const float4*)&smE[wb + (rh * 81 + c) * 12 + 4 * g];
            *(float4*)(ob + (size_t)c * CHS + (size_t)rh * Wn + 4 * g) = v;
        }
    }
}

// ---------------- fallback: verified R6 kernel (79.6 us) ----------------
__global__ __launch_bounds__(512, 4)
void corrfb(const float* __restrict__ first, const float* __restrict__ second,
            float* __restrict__ out)
{
    __shared__ uint4 smem[16 * 32 * 4];

    const int tid  = threadIdx.x;
    const int w    = tid >> 6;
    const int lane = tid & 63;
    const int quad = lane >> 4;
    const int n16  = lane & 15;
    const int r    = w;

    const int d    = (int)blockIdx.x + 10 * ((int)blockIdx.y + 12 * (int)blockIdx.z);
    const int tile = (d & 7) * 120 + (d >> 3);
    const int b    = tile / 120;
    const int rem  = tile % 120;
    const int y0   = (rem / 10) * 8;
    const int x0   = (rem % 10) * 16;
    const int y    = y0 + r;

    const float* sb = second + (size_t)b * Cn * CHS;
    int goff[4], lpos[4];
    bool val[4];
    #pragma unroll
    for (int i = 0; i < 4; ++i) {
        int e   = tid + i * 512;
        int row = e >> 7;
        int xw  = (e >> 2) & 31;
        int q   = e & 3;
        int gy  = y0 + row - 4, gx = x0 + xw - 8;
        val[i]  = (gy >= 0) && (gy < Hn) && (gx >= 0) && (gx < Wn);
        goff[i] = val[i] ? (8 * q * CHS + gy * Wn + gx) : 0;
        lpos[i] = (row * 32 + xw) * 4 + ((q + xw + (xw >> 2)) & 3);
    }

    int bo[2];
    #pragma unroll
    for (int t = 0; t < 2; ++t) {
        int xwr = 16 * t + n16;
        bo[t] = xwr * 4 + ((quad + xwr + (xwr >> 2)) & 3);
    }

    const float* fp = first + (size_t)b * Cn * CHS + (size_t)y * Wn + x0 + n16;

    f32x4 acc[9][2];
    #pragma unroll
    for (int dy = 0; dy < 9; ++dy)
        #pragma unroll
        for (int t = 0; t < 2; ++t)
            acc[dy][t] = (f32x4){0.f, 0.f, 0.f, 0.f};

    float f0[2][8];
    #pragma unroll
    for (int i = 0; i < 2; ++i)
        #pragma unroll
        for (int j = 0; j < 8; ++j)
            f0[i][j] = sb[goff[i] + (size_t)j * CHS];

    #pragma unroll
    for (int kc = 0; kc < 4; ++kc) {
        #pragma unroll
        for (int i = 0; i < 2; ++i) {
            uint4 o;
            o.x = pk(f0[i][0], f0[i][1]); o.y = pk(f0[i][2], f0[i][3]);
            o.z = pk(f0[i][4], f0[i][5]); o.w = pk(f0[i][6], f0[i][7]);
            if (!val[i]) o = make_uint4(0u, 0u, 0u, 0u);
            smem[lpos[i]] = o;
        }
        float f1[2][8], fa[8];
        #pragma unroll
        for (int i = 0; i < 2; ++i)
            #pragma unroll
            for (int j = 0; j < 8; ++j)
                f1[i][j] = sb[goff[2 + i] + (size_t)(32 * kc + j) * CHS];
        #pragma unroll
        for (int j = 0; j < 8; ++j)
            fa[j] = fp[(size_t)(32 * kc + 8 * quad + j) * CHS];
        #pragma unroll
        for (int i = 0; i < 2; ++i) {
            uint4 o;
            o.x = pk(f1[i][0], f1[i][1]); o.y = pk(f1[i][2], f1[i][3]);
            o.z = pk(f1[i][4], f1[i][5]); o.w = pk(f1[i][6], f1[i][7]);
            if (!val[2 + i]) o = make_uint4(0u, 0u, 0u, 0u);
            smem[lpos[2 + i]] = o;
        }
        bf16x8 aF;
        {
            union { uint32_t u[4]; bf16x8 v; } cv;
            cv.u[0] = pk(fa[0], fa[1]); cv.u[1] = pk(fa[2], fa[3]);
            cv.u[2] = pk(fa[4], fa[5]); cv.u[3] = pk(fa[6], fa[7]);
            aF = cv.v;
        }
        __syncthreads();
        if (kc < 3) {
            #pragma unroll
            for (int i = 0; i < 2; ++i)
                #pragma unroll
                for (int j = 0; j < 8; ++j)
                    f0[i][j] = sb[goff[i] + (size_t)(32 * (kc + 1) + j) * CHS];
        }
        #pragma unroll
        for (int dy = 0; dy < 9; ++dy) {
            const int rb = (r + dy) * 128;
            #pragma unroll
            for (int t = 0; t < 2; ++t) {
                union { uint4 u; bf16x8 v; } bf;
                bf.u = smem[rb + bo[t]];
                acc[dy][t] = __builtin_amdgcn_mfma_f32_16x16x32_bf16(
                                 aF, bf.v, acc[dy][t], 0, 0, 0);
            }
        }
        __syncthreads();
    }

    const float inv = 1.0f / 128.0f;
    float* sm = (float*)smem;
    float* ob = out + (size_t)b * 81 * CHS + (size_t)y * Wn + x0;
    const int wb = w * 540;
    #pragma unroll
    for (int ck = 0; ck < 3; ++ck) {
        #pragma unroll
        for (int dd = 0; dd < 3; ++dd)
            #pragma unroll
            for (int t = 0; t < 2; ++t)
                #pragma unroll
                for (int reg = 0; reg < 4; ++reg) {
                    int mm  = quad * 4 + reg;
                    int dxc = 16 * t + n16 - mm - 4;
                    if (dxc >= 0 && dxc <= 8)
                        sm[wb + (dd * 9 + dxc) * 20 + mm] = acc[ck * 3 + dd][t][reg] * inv;
                }
        __syncthreads();
        #pragma unroll
        for (int ii = 0; ii < 2; ++ii) {
            int slot = lane + ii * 64;
            if (slot < 108) {
                int chn = slot >> 2, g = slot & 3;
                float4 v = *(const float4*)&sm[wb + chn * 20 + 4 * g];
                int ch = (ck * 3 + chn / 9) * 9 + chn % 9;
                *(float4*)(ob + (size_t)ch * CHS + 4 * g) = v;
            }
        }
        __syncthreads();
    }
}

extern "C" void kernel_launch(void* const* d_in, const int* in_sizes, int n_in,
                              void* d_out, int out_size, void* d_ws, size_t ws_size,
                              hipStream_t stream) {
    (void)in_sizes; (void)n_in; (void)out_size;
    const float* first  = (const float*)d_in[0];
    const float* second = (const float*)d_in[1];
    float* out = (float*)d_out;

    if (ws_size >= SECP_BYTES) {
        uint4* secp = (uint4*)d_ws;
        prepass<<<dim3((unsigned)(SECP_OCTS / 256), 1, 1), dim3(256, 1, 1), 0, stream>>>(
            second, secp);
        corrmain<<<dim3(10, 12, 8), dim3(512, 1, 1), 0, stream>>>(first, secp, out);
    } else {
        corrfb<<<dim3(Wn / 16, Hn / 8, Bn), dim3(512, 1, 1), 0, stream>>>(
            first, second, out);
    }
}